// Round 2
// baseline (54.330 us; speedup 1.0000x reference)
//
#include <hip/hip_runtime.h>

#define C_DIM 256
#define K_NEIGH 32
#define NODES_PER_ITER 4

// ---------------------------------------------------------------------------
// Kernel A: complex linear projection. Persistent waves, 4 nodes per
// iteration for memory-level parallelism; weights hoisted; 4 independent
// butterfly reduction chains pipeline to hide cross-lane latency.
//   tmp[n] = (Whr[n]·Wr - Whi[n]·Wi + br,  Whr[n]·Wi + Whi[n]·Wr + bi)
// ---------------------------------------------------------------------------
__global__ __launch_bounds__(256) void proj_kernel(
    const float* __restrict__ whr, const float* __restrict__ whi,
    const float* __restrict__ wr,  const float* __restrict__ wi,
    const float* __restrict__ br,  const float* __restrict__ bi,
    float2* __restrict__ tmp, int n_nodes)
{
    const int lane   = threadIdx.x & 63;
    const int wave   = blockIdx.x * (blockDim.x >> 6) + (threadIdx.x >> 6);
    const int nwaves = gridDim.x * (blockDim.x >> 6);

    // Broadcast weights: 1 KB each, L1-resident. Loaded once per wave.
    const float4 u  = ((const float4*)wr)[lane];
    const float4 v  = ((const float4*)wi)[lane];
    const float br0 = br[0];
    const float bi0 = bi[0];

    for (int base = wave * NODES_PER_ITER; base < n_nodes;
         base += nwaves * NODES_PER_ITER) {
        const int cnt = min(NODES_PER_ITER, n_nodes - base);

        // Issue all loads up front (8 dwordx4 in flight per lane).
        float4 a[NODES_PER_ITER], b[NODES_PER_ITER];
        #pragma unroll
        for (int i = 0; i < NODES_PER_ITER; ++i) {
            if (i < cnt) {
                a[i] = ((const float4*)(whr + (size_t)(base + i) * C_DIM))[lane];
                b[i] = ((const float4*)(whi + (size_t)(base + i) * C_DIM))[lane];
            }
        }

        // Per-lane partials.
        float vr[NODES_PER_ITER], vi[NODES_PER_ITER];
        #pragma unroll
        for (int i = 0; i < NODES_PER_ITER; ++i) {
            if (i < cnt) {
                vr[i] = a[i].x*u.x + a[i].y*u.y + a[i].z*u.z + a[i].w*u.w
                      - (b[i].x*v.x + b[i].y*v.y + b[i].z*v.z + b[i].w*v.w);
                vi[i] = a[i].x*v.x + a[i].y*v.y + a[i].z*v.z + a[i].w*v.w
                      +  b[i].x*u.x + b[i].y*u.y + b[i].z*u.z + b[i].w*u.w;
            }
        }

        // 4 independent butterfly chains — interleave to pipeline the
        // cross-lane latency instead of one serial 12-deep chain.
        #pragma unroll
        for (int off = 32; off > 0; off >>= 1) {
            #pragma unroll
            for (int i = 0; i < NODES_PER_ITER; ++i) {
                vr[i] += __shfl_xor(vr[i], off, 64);
                vi[i] += __shfl_xor(vi[i], off, 64);
            }
        }

        if (lane == 0) {
            #pragma unroll
            for (int i = 0; i < NODES_PER_ITER; ++i) {
                if (i < cnt) {
                    tmp[base + i] = make_float2(vr[i] + br0, vi[i] + bi0);
                }
            }
        }
    }
}

// ---------------------------------------------------------------------------
// Kernel B: per-column attention + normalization. One thread per column m.
// Index loads coalesced (stride m_cols); tmp gathers hit L2 (800 KB table).
// ---------------------------------------------------------------------------
__global__ __launch_bounds__(256) void attn_kernel(
    const int* __restrict__ nneg, const float2* __restrict__ tmp,
    float* __restrict__ out, int m_cols)
{
    const int m = blockIdx.x * blockDim.x + threadIdx.x;
    if (m >= m_cols) return;

    const int cidx = nneg[m];             // center index (row 0)
    const float2 c = tmp[cidx];

    float att[K_NEIGH];
    float s = 0.f;
    #pragma unroll
    for (int k = 0; k < K_NEIGH; ++k) {
        const int idx = nneg[(size_t)(k + 1) * m_cols + m];
        const float2 t = tmp[idx];
        const float a = fmaxf(c.x * t.x + c.y * t.y, 0.f);
        att[k] = a;
        s += a;
    }

    const float r = 1.0f / (s + 0.001f);
    #pragma unroll
    for (int k = 0; k < K_NEIGH; ++k) {
        out[(size_t)k * m_cols + m] = att[k] * r;
    }
}

// ---------------------------------------------------------------------------
extern "C" void kernel_launch(void* const* d_in, const int* in_sizes, int n_in,
                              void* d_out, int out_size, void* d_ws, size_t ws_size,
                              hipStream_t stream)
{
    const float* whr = (const float*)d_in[0];
    const float* whi = (const float*)d_in[1];
    const int*   nng = (const int*)d_in[2];
    // d_in[3] = k_neighbors scalar (fixed = 32)
    const float* wr  = (const float*)d_in[4];
    const float* wi  = (const float*)d_in[5];
    const float* br  = (const float*)d_in[6];
    const float* bi  = (const float*)d_in[7];

    const int c_dim   = in_sizes[4];                 // 256
    const int n_nodes = in_sizes[0] / c_dim;         // 100000
    const int m_cols  = in_sizes[2] / (K_NEIGH + 1); // 100000

    float2* tmp = (float2*)d_ws;                     // 2*N floats = 800 KB

    // Kernel A: persistent grid — 2048 blocks × 4 waves = 8192 waves,
    // each grid-strides over ~13 nodes in groups of 4.
    proj_kernel<<<2048, 256, 0, stream>>>(whr, whi, wr, wi, br, bi, tmp, n_nodes);

    // Kernel B: one thread per column
    const int blocksB = (m_cols + 255) / 256;
    attn_kernel<<<blocksB, 256, 0, stream>>>(nng, tmp, (float*)d_out, m_cols);
}